// Round 10
// baseline (195.623 us; speedup 1.0000x reference)
//
#include <hip/hip_runtime.h>
#include <hip/hip_bf16.h>

// Sizes (fixed): B=1, D=H=W=16 -> L=4096, C=96, d=96, K=6, N=16, R=6
#define L 4096
#define CDIM 96
#define DDIM 96
#define KDIR 6
#define NST 16
#define RRK 6
#define YH 32        // Y2h row: B at [0..15], C at [16..31] (half)
#define NCHUNK 256
#define CHLEN 16     // NCHUNK*CHLEN == L

typedef _Float16 half4v __attribute__((ext_vector_type(4)));
typedef _Float16 half2v __attribute__((ext_vector_type(2)));

__device__ __forceinline__ float sigmoidf_(float x) { return 1.f / (1.f + __expf(-x)); }

// scan-position l -> spatial index s for base direction kb in {0,1,2}
__device__ __forceinline__ int sigma_k(int kb, int l) {
    if (kb == 0) return l;
    if (kb == 1) return ((l & 15) << 8) | ((l >> 8) << 4) | ((l >> 4) & 15);
    return (((l >> 4) & 15) << 8) | ((l & 15) << 4) | (l >> 8);
}

// K1: LN + in_proj, weight-in-registers, 8 spatial rows per block.
__global__ void __launch_bounds__(192) k1_ln_inproj(
        const float* __restrict__ x, const float* __restrict__ ln_w,
        const float* __restrict__ ln_b, const float* __restrict__ Wp,
        _Float16* __restrict__ xhh, _Float16* __restrict__ zsh) {
    int s0 = blockIdx.x * 8;
    int tid = threadIdx.x;
    __shared__ __align__(16) float xt[8][96];
    __shared__ __align__(16) float xn[8][96];
    __shared__ float mss[8], rss[8];
    ((float4*)&xt[0][0])[tid] = ((const float4*)(x + (size_t)s0 * 96))[tid];
    __syncthreads();
    int wave = tid >> 6, lane = tid & 63;
    for (int r = wave; r < 8; r += 3) {
        float v = xt[r][lane] + ((lane < 32) ? xt[r][64 + lane] : 0.f);
#pragma unroll
        for (int off = 1; off < 64; off <<= 1) v += __shfl_xor(v, off);
        float vs = xt[r][lane] * xt[r][lane] + ((lane < 32) ? xt[r][64 + lane] * xt[r][64 + lane] : 0.f);
#pragma unroll
        for (int off = 1; off < 64; off <<= 1) vs += __shfl_xor(vs, off);
        if (lane == 0) {
            float mean = v * (1.f / 96.f);
            float var = vs * (1.f / 96.f) - mean * mean;
            mss[r] = mean; rss[r] = rsqrtf(var + 1e-6f);
        }
    }
    __syncthreads();
    {
        int r = tid / 24, c4 = tid % 24;
        float4 xv = ((float4*)&xt[r][0])[c4];
        float4 wv = ((const float4*)ln_w)[c4];
        float4 bv = ((const float4*)ln_b)[c4];
        float m = mss[r], rs = rss[r];
        float4 o;
        o.x = (xv.x - m) * rs * wv.x + bv.x;
        o.y = (xv.y - m) * rs * wv.y + bv.y;
        o.z = (xv.z - m) * rs * wv.z + bv.z;
        o.w = (xv.w - m) * rs * wv.w + bv.w;
        ((float4*)&xn[r][0])[c4] = o;
    }
    float4 Wr[24];
    const float4* wr = (const float4*)(Wp + (size_t)tid * 96);
#pragma unroll
    for (int c4 = 0; c4 < 24; c4++) Wr[c4] = wr[c4];
    __syncthreads();
#pragma unroll
    for (int s = 0; s < 8; s++) {
        const float4* xr4 = (const float4*)&xn[s][0];
        float a0 = 0.f, a1 = 0.f, a2 = 0.f, a3 = 0.f;
#pragma unroll
        for (int c4 = 0; c4 < 24; c4 += 4) {
            float4 x0 = xr4[c4], x1 = xr4[c4 + 1], x2 = xr4[c4 + 2], x3 = xr4[c4 + 3];
            a0 += Wr[c4].x * x0.x + Wr[c4].y * x0.y + Wr[c4].z * x0.z + Wr[c4].w * x0.w;
            a1 += Wr[c4+1].x * x1.x + Wr[c4+1].y * x1.y + Wr[c4+1].z * x1.z + Wr[c4+1].w * x1.w;
            a2 += Wr[c4+2].x * x2.x + Wr[c4+2].y * x2.y + Wr[c4+2].z * x2.z + Wr[c4+2].w * x2.w;
            a3 += Wr[c4+3].x * x3.x + Wr[c4+3].y * x3.y + Wr[c4+3].z * x3.z + Wr[c4+3].w * x3.w;
        }
        float acc = (a0 + a1) + (a2 + a3);
        if (tid < 96) xhh[(size_t)tid * L + s0 + s] = (_Float16)acc;
        else zsh[(size_t)(s0 + s) * 96 + (tid - 96)] = (_Float16)(acc * sigmoidf_(acc));
    }
}

// K2: depthwise 3x3x3 conv (SAME) + bias + SiLU; writes xch[c][s] and xcTh[s][c]
__global__ void k2_conv(const _Float16* __restrict__ xhh, const float* __restrict__ cw,
                        const float* __restrict__ cb, _Float16* __restrict__ xch,
                        _Float16* __restrict__ xcTh) {
    int idx = blockIdx.x * 256 + threadIdx.x; // 96*4096
    int c = idx >> 12, s = idx & 4095;
    int dz = s >> 8, h = (s >> 4) & 15, w = s & 15;
    const _Float16* xin = xhh + (size_t)c * L;
    const float* wc = cw + c * 27;
    float acc = cb[c];
#pragma unroll
    for (int i = 0; i < 3; i++) {
        int z2 = dz + i - 1; if ((unsigned)z2 > 15u) continue;
#pragma unroll
        for (int j = 0; j < 3; j++) {
            int h2 = h + j - 1; if ((unsigned)h2 > 15u) continue;
#pragma unroll
            for (int kk = 0; kk < 3; kk++) {
                int w2 = w + kk - 1; if ((unsigned)w2 > 15u) continue;
                acc += (float)xin[z2 * 256 + h2 * 16 + w2] * wc[i * 9 + j * 3 + kk];
            }
        }
    }
    float r = acc * sigmoidf_(acc);
    _Float16 hr = (_Float16)r;
    xch[(size_t)c * L + s] = hr;
    xcTh[(size_t)s * 96 + c] = hr;
}

// K3 (+fused K4, balanced): grid (6,16,4). Group g computes the 6 dt channels
// (redundantly) + 8 B/C channels, then expands dt -> Zsh for its 24-of-96 d-range.
__global__ void k3_xproj(const _Float16* __restrict__ xch, const float* __restrict__ Wx,
                         const float* __restrict__ Wdt, const float* __restrict__ bdt,
                         _Float16* __restrict__ Y2h, _Float16* __restrict__ Zsh) {
    int k = blockIdx.x;
    int tid = threadIdx.x;
    int sbase = blockIdx.y * 256;
    int s = sbase + tid;
    int g = blockIdx.z;   // 0..3
    __shared__ float dts[256][6];
    float acc[14];
#pragma unroll
    for (int i = 0; i < 14; i++) acc[i] = 0.f;
    const float* wdt_rows = Wx + (size_t)k * 38 * DDIM;                 // channels 0..5
    const float* wbc      = Wx + ((size_t)k * 38 + 6 + g * 8) * DDIM;   // 8 B/C channels
    for (int dd = 0; dd < 96; dd += 4) {
        float v[4];
#pragma unroll
        for (int j = 0; j < 4; j++) v[j] = (float)xch[(size_t)(dd + j) * L + s];
#pragma unroll
        for (int j = 0; j < 4; j++) {
#pragma unroll
            for (int r = 0; r < 6; r++) acc[r] += wdt_rows[r * DDIM + dd + j] * v[j];
#pragma unroll
            for (int i = 0; i < 8; i++) acc[6 + i] += wbc[i * DDIM + dd + j] * v[j];
        }
    }
    _Float16* yo = Y2h + ((size_t)k * L + s) * YH;
#pragma unroll
    for (int i = 0; i < 8; i++) yo[g * 8 + i] = (_Float16)acc[6 + i];
#pragma unroll
    for (int r = 0; r < 6; r++) dts[tid][r] = acc[r];
    __syncthreads();
    for (int i = 0; i < 24; i++) {
        int idx = i * 256 + tid;      // < 6144 = 256 sr * 24 dl
        int dl = idx % 24;
        int sr = idx / 24;
        int d = g * 24 + dl;
        const float* wr = Wdt + ((size_t)k * 96 + d) * 6;
        float a = bdt[k * 96 + d];
#pragma unroll
        for (int r = 0; r < 6; r++) a += wr[r] * dts[sr][r];
        float sp = (a > 15.f) ? a : __logf(1.f + __expf(a));
        Zsh[((size_t)k * L + sbase + sr) * 96 + d] = (_Float16)sp;
    }
}

// ---- 3-phase chunked scan, 4 states/thread, fp16, chunk-contiguous state ----
// state layout: [k][d][n][chunk]   (chunk fastest -> kb fully coalesced)
// ka/kc thread t: nq = t&3, d = (t>>2)%96, chunk = ((t>>2)/96)%NCHUNK, k = ...

__global__ void __launch_bounds__(256) ka_scan(
        const _Float16* __restrict__ Zsh, const _Float16* __restrict__ xcTh,
        const _Float16* __restrict__ Y2h, const float* __restrict__ A_log,
        _Float16* __restrict__ Aah, _Float16* __restrict__ Abh) {
    int t = blockIdx.x * 256 + threadIdx.x;
    int nq = t & 3;
    int q = t >> 2;
    int d = q % 96;
    int rest = q / 96;
    int chunk = rest % NCHUNK;
    int k = rest / NCHUNK;
    int kb = (k < 3) ? k : (k - 3);
    bool flip = (k >= 3);
    float An[4];
    {
        float4 al = *(const float4*)(A_log + ((size_t)k * 96 + d) * 16 + nq * 4);
        An[0] = -__expf(al.x); An[1] = -__expf(al.y);
        An[2] = -__expf(al.z); An[3] = -__expf(al.w);
    }
    float a[4] = {1.f, 1.f, 1.f, 1.f};
    float b[4] = {0.f, 0.f, 0.f, 0.f};
    const _Float16* Zk = Zsh + (size_t)k * L * 96;
    const _Float16* Yk = Y2h + (size_t)k * L * YH;
    int l0 = chunk * CHLEN;
    for (int i = 0; i < CHLEN; i += 4) {
        int sI[4]; float dt[4], xv[4]; half4v Bh[4];
#pragma unroll
        for (int j = 0; j < 4; j++) {
            int l = l0 + i + j;
            int lp = flip ? (4095 - l) : l;
            sI[j] = sigma_k(kb, lp);
        }
#pragma unroll
        for (int j = 0; j < 4; j++) {
            dt[j] = (float)Zk[(size_t)sI[j] * 96 + d];
            xv[j] = (float)xcTh[(size_t)sI[j] * 96 + d];
            Bh[j] = *(const half4v*)(Yk + (size_t)sI[j] * YH + nq * 4);
        }
#pragma unroll
        for (int j = 0; j < 4; j++) {
            float dtx = dt[j] * xv[j];
            float e0 = __expf(dt[j] * An[0]);
            float e1 = __expf(dt[j] * An[1]);
            float e2 = __expf(dt[j] * An[2]);
            float e3 = __expf(dt[j] * An[3]);
            b[0] = e0 * b[0] + dtx * (float)Bh[j].x; a[0] *= e0;
            b[1] = e1 * b[1] + dtx * (float)Bh[j].y; a[1] *= e1;
            b[2] = e2 * b[2] + dtx * (float)Bh[j].z; a[2] *= e2;
            b[3] = e3 * b[3] + dtx * (float)Bh[j].w; a[3] *= e3;
        }
    }
    // scatter into chunk-contiguous layout
    size_t colbase = ((size_t)(k * 96 + d) * 16 + nq * 4) * NCHUNK + chunk;
#pragma unroll
    for (int j = 0; j < 4; j++) {
        Aah[colbase + (size_t)j * NCHUNK] = (_Float16)a[j];
        Abh[colbase + (size_t)j * NCHUNK] = (_Float16)b[j];
    }
}

// Phase B: one WAVE per (k,d,n) column; lane i owns chunks 4i..4i+3 (coalesced half4).
// Affine compose: applying earlier (A',B') then current (A,B): Anew=A*A', Bnew=A*B'+B.
__global__ void __launch_bounds__(256) kb_combine(
        const _Float16* __restrict__ Aah, const _Float16* __restrict__ Abh,
        _Float16* __restrict__ Pbh) {
    int w = blockIdx.x * 4 + (threadIdx.x >> 6);   // wave id < 9216
    int lane = threadIdx.x & 63;
    size_t colbase = (size_t)w * NCHUNK;
    half4v ha = *(const half4v*)(Aah + colbase + lane * 4);
    half4v hb = *(const half4v*)(Abh + colbase + lane * 4);
    float a0 = (float)ha.x, a1 = (float)ha.y, a2 = (float)ha.z, a3 = (float)ha.w;
    float b0 = (float)hb.x, b1 = (float)hb.y, b2 = (float)hb.z, b3 = (float)hb.w;
    // local compose of the 4 chunks (in order): h -> A*h + B
    float A = a0 * a1 * a2 * a3;
    float B = ((b0 * a1 + b1) * a2 + b2) * a3 + b3;
    // inclusive wave scan of (A,B)
#pragma unroll
    for (int off = 1; off < 64; off <<= 1) {
        float Ap = __shfl_up(A, off);
        float Bp = __shfl_up(B, off);
        if (lane >= off) { B = A * Bp + B; A = A * Ap; }
    }
    // exclusive carry into this lane's first chunk = inclusive B of lane-1
    float carry = __shfl_up(B, 1);
    if (lane == 0) carry = 0.f;
    // per-chunk exclusive prefixes
    float P0 = carry;
    float P1 = a0 * P0 + b0;
    float P2 = a1 * P1 + b1;
    float P3 = a2 * P2 + b2;
    half4v hp;
    hp.x = (_Float16)P0; hp.y = (_Float16)P1; hp.z = (_Float16)P2; hp.w = (_Float16)P3;
    *(half4v*)(Pbh + colbase + lane * 4) = hp;
}

// Phase C: re-scan with carry, fuse y = sum_n h*C + D*x; ysh layout [s][d][k]
__global__ void __launch_bounds__(256) kc_apply(
        const _Float16* __restrict__ Zsh, const _Float16* __restrict__ xcTh,
        const _Float16* __restrict__ Y2h, const float* __restrict__ A_log,
        const float* __restrict__ D_skip, const _Float16* __restrict__ Pbh,
        _Float16* __restrict__ ysh) {
    int t = blockIdx.x * 256 + threadIdx.x;
    int nq = t & 3;
    int q = t >> 2;
    int d = q % 96;
    int rest = q / 96;
    int chunk = rest % NCHUNK;
    int k = rest / NCHUNK;
    int kb = (k < 3) ? k : (k - 3);
    bool flip = (k >= 3);
    float An[4];
    {
        float4 al = *(const float4*)(A_log + ((size_t)k * 96 + d) * 16 + nq * 4);
        An[0] = -__expf(al.x); An[1] = -__expf(al.y);
        An[2] = -__expf(al.z); An[3] = -__expf(al.w);
    }
    float Dk = D_skip[k * DDIM + d];
    float h[4];
    {
        size_t colbase = ((size_t)(k * 96 + d) * 16 + nq * 4) * NCHUNK + chunk;
#pragma unroll
        for (int j = 0; j < 4; j++) h[j] = (float)Pbh[colbase + (size_t)j * NCHUNK];
    }
    const _Float16* Zk = Zsh + (size_t)k * L * 96;
    const _Float16* Yk = Y2h + (size_t)k * L * YH;
    int l0 = chunk * CHLEN;
    for (int i = 0; i < CHLEN; i += 4) {
        int sI[4]; float dt[4], xv[4]; half4v Bh[4], Ch[4];
#pragma unroll
        for (int j = 0; j < 4; j++) {
            int l = l0 + i + j;
            int lp = flip ? (4095 - l) : l;
            sI[j] = sigma_k(kb, lp);
        }
#pragma unroll
        for (int j = 0; j < 4; j++) {
            dt[j] = (float)Zk[(size_t)sI[j] * 96 + d];
            xv[j] = (float)xcTh[(size_t)sI[j] * 96 + d];
            Bh[j] = *(const half4v*)(Yk + (size_t)sI[j] * YH + nq * 4);
            Ch[j] = *(const half4v*)(Yk + (size_t)sI[j] * YH + 16 + nq * 4);
        }
#pragma unroll
        for (int j = 0; j < 4; j++) {
            float dtx = dt[j] * xv[j];
            float e0 = __expf(dt[j] * An[0]);
            float e1 = __expf(dt[j] * An[1]);
            float e2 = __expf(dt[j] * An[2]);
            float e3 = __expf(dt[j] * An[3]);
            h[0] = e0 * h[0] + dtx * (float)Bh[j].x;
            h[1] = e1 * h[1] + dtx * (float)Bh[j].y;
            h[2] = e2 * h[2] + dtx * (float)Bh[j].z;
            h[3] = e3 * h[3] + dtx * (float)Bh[j].w;
            float p = h[0] * (float)Ch[j].x + h[1] * (float)Ch[j].y
                    + h[2] * (float)Ch[j].z + h[3] * (float)Ch[j].w;
            p += __shfl_xor(p, 1);
            p += __shfl_xor(p, 2);
            if (nq == 0) ysh[((size_t)sI[j] * 96 + d) * KDIR + k] = (_Float16)(p + Dk * xv[j]);
        }
    }
}

// K6: weight-in-registers out stage. 8 s-rows per block, 192 thr, grid 512.
// ysh layout [s][d][k]: 6 direction values contiguous (12 B -> 3x half2).
__global__ void __launch_bounds__(192) k6_out(
        const _Float16* __restrict__ ysh, const _Float16* __restrict__ zsh,
        const float* __restrict__ onw, const float* __restrict__ onb,
        const float* __restrict__ Wo, const float* __restrict__ x,
        float* __restrict__ out) {
    int s0 = blockIdx.x * 8;
    int tid = threadIdx.x;
    __shared__ __align__(16) float vt[8][96];
    __shared__ __align__(16) float gt[8][96];
    __shared__ float mss[8], rss[8];
#pragma unroll
    for (int j = 0; j < 4; j++) {
        int f = tid + j * 192;           // < 768
        int sr = f / 96, c = f % 96;
        const half2v* yr = (const half2v*)(ysh + ((size_t)(s0 + sr) * 96 + c) * KDIR);
        half2v y0 = yr[0], y1 = yr[1], y2 = yr[2];
        vt[sr][c] = (float)y0.x + (float)y0.y + (float)y1.x + (float)y1.y
                  + (float)y2.x + (float)y2.y;
    }
    __syncthreads();
    int wave = tid >> 6, lane = tid & 63;
    for (int r = wave; r < 8; r += 3) {
        float v = vt[r][lane] + ((lane < 32) ? vt[r][64 + lane] : 0.f);
#pragma unroll
        for (int off = 1; off < 64; off <<= 1) v += __shfl_xor(v, off);
        float vs = vt[r][lane] * vt[r][lane] + ((lane < 32) ? vt[r][64 + lane] * vt[r][64 + lane] : 0.f);
#pragma unroll
        for (int off = 1; off < 64; off <<= 1) vs += __shfl_xor(vs, off);
        if (lane == 0) {
            float mean = v * (1.f / 96.f);
            float var = vs * (1.f / 96.f) - mean * mean;
            mss[r] = mean; rss[r] = rsqrtf(var + 1e-5f);
        }
    }
    __syncthreads();
#pragma unroll
    for (int j = 0; j < 4; j++) {
        int f = tid + j * 192;
        int sr = f / 96, c = f % 96;
        float g = (vt[sr][c] - mss[sr]) * rss[sr] * onw[c] + onb[c];
        gt[sr][c] = g * (float)zsh[(size_t)(s0 + sr) * 96 + c];
    }
    int e = tid % 96, sg = tid / 96;  // sg in {0,1}
    float4 Wr[24];
    const float4* wr = (const float4*)(Wo + (size_t)e * 96);
#pragma unroll
    for (int c4 = 0; c4 < 24; c4++) Wr[c4] = wr[c4];
    __syncthreads();
#pragma unroll
    for (int j = 0; j < 4; j++) {
        int s = sg * 4 + j;
        const float4* g4 = (const float4*)&gt[s][0];
        float a0 = 0.f, a1 = 0.f, a2 = 0.f, a3 = 0.f;
#pragma unroll
        for (int c4 = 0; c4 < 24; c4 += 4) {
            float4 x0 = g4[c4], x1 = g4[c4 + 1], x2 = g4[c4 + 2], x3 = g4[c4 + 3];
            a0 += Wr[c4].x * x0.x + Wr[c4].y * x0.y + Wr[c4].z * x0.z + Wr[c4].w * x0.w;
            a1 += Wr[c4+1].x * x1.x + Wr[c4+1].y * x1.y + Wr[c4+1].z * x1.z + Wr[c4+1].w * x1.w;
            a2 += Wr[c4+2].x * x2.x + Wr[c4+2].y * x2.y + Wr[c4+2].z * x2.z + Wr[c4+2].w * x2.w;
            a3 += Wr[c4+3].x * x3.x + Wr[c4+3].y * x3.y + Wr[c4+3].z * x3.z + Wr[c4+3].w * x3.w;
        }
        float acc = (a0 + a1) + (a2 + a3) + x[(size_t)(s0 + s) * 96 + e];
        out[(size_t)(s0 + s) * 96 + e] = acc;
    }
}

extern "C" void kernel_launch(void* const* d_in, const int* in_sizes, int n_in,
                              void* d_out, int out_size, void* d_ws, size_t ws_size,
                              hipStream_t stream) {
    const float* x        = (const float*)d_in[0];
    const float* ln1_w    = (const float*)d_in[1];
    const float* ln1_b    = (const float*)d_in[2];
    const float* in_proj  = (const float*)d_in[3];
    const float* conv_w   = (const float*)d_in[4];
    const float* conv_b   = (const float*)d_in[5];
    const float* x_proj   = (const float*)d_in[6];
    const float* dt_w     = (const float*)d_in[7];
    const float* dt_b     = (const float*)d_in[8];
    const float* A_log    = (const float*)d_in[9];
    const float* D_skip   = (const float*)d_in[10];
    const float* onw      = (const float*)d_in[11];
    const float* onb      = (const float*)d_in[12];
    const float* out_w    = (const float*)d_in[13];
    float* out = (float*)d_out;

    _Float16* xhh  = (_Float16*)d_ws;                 // 96*4096
    _Float16* zsh  = xhh + (size_t)96 * L;            // 4096*96
    _Float16* xch  = zsh + (size_t)96 * L;            // 96*4096
    _Float16* xcTh = xch + (size_t)96 * L;            // 4096*96
    _Float16* Y2h  = xcTh + (size_t)96 * L;           // 6*4096*32
    _Float16* Zsh  = Y2h + (size_t)KDIR * L * YH;     // 6*4096*96
    _Float16* ysh  = Zsh + (size_t)KDIR * L * 96;     // 4096*96*6
    _Float16* Aah  = ysh + (size_t)L * 96 * KDIR;     // 6*96*16*256 (chunk-contig)
    _Float16* Abh  = Aah + (size_t)KDIR * DDIM * NST * NCHUNK;
    _Float16* Pbh  = Abh + (size_t)KDIR * DDIM * NST * NCHUNK;

    k1_ln_inproj<<<dim3(L / 8), dim3(192), 0, stream>>>(x, ln1_w, ln1_b, in_proj, xhh, zsh);
    k2_conv<<<dim3(96 * L / 256), dim3(256), 0, stream>>>(xhh, conv_w, conv_b, xch, xcTh);
    k3_xproj<<<dim3(KDIR, 16, 4), dim3(256), 0, stream>>>(xch, x_proj, dt_w, dt_b, Y2h, Zsh);
    ka_scan<<<dim3(KDIR * NCHUNK * DDIM * 4 / 256), dim3(256), 0, stream>>>(Zsh, xcTh, Y2h, A_log, Aah, Abh);
    kb_combine<<<dim3(KDIR * DDIM * NST / 4), dim3(256), 0, stream>>>(Aah, Abh, Pbh);
    kc_apply<<<dim3(KDIR * NCHUNK * DDIM * 4 / 256), dim3(256), 0, stream>>>(Zsh, xcTh, Y2h, A_log, D_skip, Pbh, ysh);
    k6_out<<<dim3(L / 8), dim3(192), 0, stream>>>(ysh, zsh, onw, onb, out_w, x, out);
}

// Round 11
// 178.681 us; speedup vs baseline: 1.0948x; 1.0948x over previous
//
#include <hip/hip_runtime.h>
#include <hip/hip_bf16.h>

// Sizes (fixed): B=1, D=H=W=16 -> L=4096, C=96, d=96, K=6, N=16, R=6
#define L 4096
#define CDIM 96
#define DDIM 96
#define KDIR 6
#define NST 16
#define RRK 6
#define YH 32        // Y2h row: B at [0..15], C at [16..31] (half)
#define NCHUNK 256
#define CHLEN 16     // NCHUNK*CHLEN == L

typedef _Float16 half4v __attribute__((ext_vector_type(4)));

__device__ __forceinline__ float sigmoidf_(float x) { return 1.f / (1.f + __expf(-x)); }

// scan-position l -> spatial index s for base direction kb in {0,1,2}
__device__ __forceinline__ int sigma_k(int kb, int l) {
    if (kb == 0) return l;
    if (kb == 1) return ((l & 15) << 8) | ((l >> 8) << 4) | ((l >> 4) & 15);
    return (((l >> 4) & 15) << 8) | ((l & 15) << 4) | (l >> 8);
}

// K1: LN + in_proj, weight-in-registers, 8 spatial rows per block.
__global__ void __launch_bounds__(192) k1_ln_inproj(
        const float* __restrict__ x, const float* __restrict__ ln_w,
        const float* __restrict__ ln_b, const float* __restrict__ Wp,
        _Float16* __restrict__ xhh, _Float16* __restrict__ zsh) {
    int s0 = blockIdx.x * 8;
    int tid = threadIdx.x;
    __shared__ __align__(16) float xt[8][96];
    __shared__ __align__(16) float xn[8][96];
    __shared__ float mss[8], rss[8];
    ((float4*)&xt[0][0])[tid] = ((const float4*)(x + (size_t)s0 * 96))[tid];
    __syncthreads();
    int wave = tid >> 6, lane = tid & 63;
    for (int r = wave; r < 8; r += 3) {
        float v = xt[r][lane] + ((lane < 32) ? xt[r][64 + lane] : 0.f);
#pragma unroll
        for (int off = 1; off < 64; off <<= 1) v += __shfl_xor(v, off);
        float vs = xt[r][lane] * xt[r][lane] + ((lane < 32) ? xt[r][64 + lane] * xt[r][64 + lane] : 0.f);
#pragma unroll
        for (int off = 1; off < 64; off <<= 1) vs += __shfl_xor(vs, off);
        if (lane == 0) {
            float mean = v * (1.f / 96.f);
            float var = vs * (1.f / 96.f) - mean * mean;
            mss[r] = mean; rss[r] = rsqrtf(var + 1e-6f);
        }
    }
    __syncthreads();
    {
        int r = tid / 24, c4 = tid % 24;
        float4 xv = ((float4*)&xt[r][0])[c4];
        float4 wv = ((const float4*)ln_w)[c4];
        float4 bv = ((const float4*)ln_b)[c4];
        float m = mss[r], rs = rss[r];
        float4 o;
        o.x = (xv.x - m) * rs * wv.x + bv.x;
        o.y = (xv.y - m) * rs * wv.y + bv.y;
        o.z = (xv.z - m) * rs * wv.z + bv.z;
        o.w = (xv.w - m) * rs * wv.w + bv.w;
        ((float4*)&xn[r][0])[c4] = o;
    }
    float4 Wr[24];
    const float4* wr = (const float4*)(Wp + (size_t)tid * 96);
#pragma unroll
    for (int c4 = 0; c4 < 24; c4++) Wr[c4] = wr[c4];
    __syncthreads();
#pragma unroll
    for (int s = 0; s < 8; s++) {
        const float4* xr4 = (const float4*)&xn[s][0];
        float a0 = 0.f, a1 = 0.f, a2 = 0.f, a3 = 0.f;
#pragma unroll
        for (int c4 = 0; c4 < 24; c4 += 4) {
            float4 x0 = xr4[c4], x1 = xr4[c4 + 1], x2 = xr4[c4 + 2], x3 = xr4[c4 + 3];
            a0 += Wr[c4].x * x0.x + Wr[c4].y * x0.y + Wr[c4].z * x0.z + Wr[c4].w * x0.w;
            a1 += Wr[c4+1].x * x1.x + Wr[c4+1].y * x1.y + Wr[c4+1].z * x1.z + Wr[c4+1].w * x1.w;
            a2 += Wr[c4+2].x * x2.x + Wr[c4+2].y * x2.y + Wr[c4+2].z * x2.z + Wr[c4+2].w * x2.w;
            a3 += Wr[c4+3].x * x3.x + Wr[c4+3].y * x3.y + Wr[c4+3].z * x3.z + Wr[c4+3].w * x3.w;
        }
        float acc = (a0 + a1) + (a2 + a3);
        if (tid < 96) xhh[(size_t)tid * L + s0 + s] = (_Float16)acc;
        else zsh[(size_t)(s0 + s) * 96 + (tid - 96)] = (_Float16)(acc * sigmoidf_(acc));
    }
}

// K2: depthwise 3x3x3 conv (SAME) + bias + SiLU; writes xch[c][s] and xcTh[s][c]
__global__ void k2_conv(const _Float16* __restrict__ xhh, const float* __restrict__ cw,
                        const float* __restrict__ cb, _Float16* __restrict__ xch,
                        _Float16* __restrict__ xcTh) {
    int idx = blockIdx.x * 256 + threadIdx.x; // 96*4096
    int c = idx >> 12, s = idx & 4095;
    int dz = s >> 8, h = (s >> 4) & 15, w = s & 15;
    const _Float16* xin = xhh + (size_t)c * L;
    const float* wc = cw + c * 27;
    float acc = cb[c];
#pragma unroll
    for (int i = 0; i < 3; i++) {
        int z2 = dz + i - 1; if ((unsigned)z2 > 15u) continue;
#pragma unroll
        for (int j = 0; j < 3; j++) {
            int h2 = h + j - 1; if ((unsigned)h2 > 15u) continue;
#pragma unroll
            for (int kk = 0; kk < 3; kk++) {
                int w2 = w + kk - 1; if ((unsigned)w2 > 15u) continue;
                acc += (float)xin[z2 * 256 + h2 * 16 + w2] * wc[i * 9 + j * 3 + kk];
            }
        }
    }
    float r = acc * sigmoidf_(acc);
    _Float16 hr = (_Float16)r;
    xch[(size_t)c * L + s] = hr;
    xcTh[(size_t)s * 96 + c] = hr;
}

// K3 (+fused K4, balanced): grid (6,16,4). Group g computes the 6 dt channels
// (redundantly) + 8 B/C channels, then expands dt -> Zsh for its 24-of-96 d-range.
__global__ void k3_xproj(const _Float16* __restrict__ xch, const float* __restrict__ Wx,
                         const float* __restrict__ Wdt, const float* __restrict__ bdt,
                         _Float16* __restrict__ Y2h, _Float16* __restrict__ Zsh) {
    int k = blockIdx.x;
    int tid = threadIdx.x;
    int sbase = blockIdx.y * 256;
    int s = sbase + tid;
    int g = blockIdx.z;   // 0..3
    __shared__ float dts[256][6];
    float acc[14];
#pragma unroll
    for (int i = 0; i < 14; i++) acc[i] = 0.f;
    const float* wdt_rows = Wx + (size_t)k * 38 * DDIM;                 // channels 0..5
    const float* wbc      = Wx + ((size_t)k * 38 + 6 + g * 8) * DDIM;   // 8 B/C channels
    for (int dd = 0; dd < 96; dd += 4) {
        float v[4];
#pragma unroll
        for (int j = 0; j < 4; j++) v[j] = (float)xch[(size_t)(dd + j) * L + s];
#pragma unroll
        for (int j = 0; j < 4; j++) {
#pragma unroll
            for (int r = 0; r < 6; r++) acc[r] += wdt_rows[r * DDIM + dd + j] * v[j];
#pragma unroll
            for (int i = 0; i < 8; i++) acc[6 + i] += wbc[i * DDIM + dd + j] * v[j];
        }
    }
    _Float16* yo = Y2h + ((size_t)k * L + s) * YH;
#pragma unroll
    for (int i = 0; i < 8; i++) yo[g * 8 + i] = (_Float16)acc[6 + i];
#pragma unroll
    for (int r = 0; r < 6; r++) dts[tid][r] = acc[r];
    __syncthreads();
    for (int i = 0; i < 24; i++) {
        int idx = i * 256 + tid;      // < 6144 = 256 sr * 24 dl
        int dl = idx % 24;
        int sr = idx / 24;
        int d = g * 24 + dl;
        const float* wr = Wdt + ((size_t)k * 96 + d) * 6;
        float a = bdt[k * 96 + d];
#pragma unroll
        for (int r = 0; r < 6; r++) a += wr[r] * dts[sr][r];
        float sp = (a > 15.f) ? a : __logf(1.f + __expf(a));
        Zsh[((size_t)k * L + sbase + sr) * 96 + d] = (_Float16)sp;
    }
}

// ---- 3-phase chunked scan, 4 states/thread (nq = t&3), fp16 everywhere ----
// state layout: [k][chunk][d][16]  (d-coalesced for ka/kc)

__global__ void __launch_bounds__(256) ka_scan(
        const _Float16* __restrict__ Zsh, const _Float16* __restrict__ xcTh,
        const _Float16* __restrict__ Y2h, const float* __restrict__ A_log,
        _Float16* __restrict__ Aah, _Float16* __restrict__ Abh) {
    int t = blockIdx.x * 256 + threadIdx.x;
    int nq = t & 3;
    int q = t >> 2;
    int d = q % 96;
    int rest = q / 96;
    int chunk = rest % NCHUNK;
    int k = rest / NCHUNK;
    int kb = (k < 3) ? k : (k - 3);
    bool flip = (k >= 3);
    float An[4];
    {
        float4 al = *(const float4*)(A_log + ((size_t)k * 96 + d) * 16 + nq * 4);
        An[0] = -__expf(al.x); An[1] = -__expf(al.y);
        An[2] = -__expf(al.z); An[3] = -__expf(al.w);
    }
    float a[4] = {1.f, 1.f, 1.f, 1.f};
    float b[4] = {0.f, 0.f, 0.f, 0.f};
    const _Float16* Zk = Zsh + (size_t)k * L * 96;
    const _Float16* Yk = Y2h + (size_t)k * L * YH;
    int l0 = chunk * CHLEN;
    for (int i = 0; i < CHLEN; i += 4) {
        int sI[4]; float dt[4], xv[4]; half4v Bh[4];
#pragma unroll
        for (int j = 0; j < 4; j++) {
            int l = l0 + i + j;
            int lp = flip ? (4095 - l) : l;
            sI[j] = sigma_k(kb, lp);
        }
#pragma unroll
        for (int j = 0; j < 4; j++) {
            dt[j] = (float)Zk[(size_t)sI[j] * 96 + d];
            xv[j] = (float)xcTh[(size_t)sI[j] * 96 + d];
            Bh[j] = *(const half4v*)(Yk + (size_t)sI[j] * YH + nq * 4);
        }
#pragma unroll
        for (int j = 0; j < 4; j++) {
            float dtx = dt[j] * xv[j];
            float e0 = __expf(dt[j] * An[0]);
            float e1 = __expf(dt[j] * An[1]);
            float e2 = __expf(dt[j] * An[2]);
            float e3 = __expf(dt[j] * An[3]);
            b[0] = e0 * b[0] + dtx * (float)Bh[j].x; a[0] *= e0;
            b[1] = e1 * b[1] + dtx * (float)Bh[j].y; a[1] *= e1;
            b[2] = e2 * b[2] + dtx * (float)Bh[j].z; a[2] *= e2;
            b[3] = e3 * b[3] + dtx * (float)Bh[j].w; a[3] *= e3;
        }
    }
    size_t o = (((size_t)k * NCHUNK + chunk) * 96 + d) * 16 + nq * 4;
    half4v ha, hb;
    ha.x = (_Float16)a[0]; ha.y = (_Float16)a[1]; ha.z = (_Float16)a[2]; ha.w = (_Float16)a[3];
    hb.x = (_Float16)b[0]; hb.y = (_Float16)b[1]; hb.z = (_Float16)b[2]; hb.w = (_Float16)b[3];
    *(half4v*)(Aah + o) = ha;
    *(half4v*)(Abh + o) = hb;
}

// Phase B: serial combine across 256 chunks per (k,d,n); fp16 in/out
__global__ void __launch_bounds__(256) kb_combine(
        const _Float16* __restrict__ Aah, const _Float16* __restrict__ Abh,
        _Float16* __restrict__ Pbh) {
    int t = blockIdx.x * 256 + threadIdx.x;  // < 6*96*16 = 9216
    int n = t & 15;
    int rest = t >> 4;
    int d = rest % 96;
    int k = rest / 96;
    size_t base = ((size_t)k * NCHUNK * 96 + d) * 16 + n;
    const size_t cstride = 96 * 16;
    float rb = 0.f;
    for (int c0 = 0; c0 < NCHUNK; c0 += 16) {
        float av[16], bv[16];
#pragma unroll
        for (int j = 0; j < 16; j++) {
            av[j] = (float)Aah[base + (size_t)(c0 + j) * cstride];
            bv[j] = (float)Abh[base + (size_t)(c0 + j) * cstride];
        }
#pragma unroll
        for (int j = 0; j < 16; j++) {
            Pbh[base + (size_t)(c0 + j) * cstride] = (_Float16)rb;
            rb = av[j] * rb + bv[j];
        }
    }
}

// Phase C: re-scan with carry, fuse y = sum_n h*C + D*x; ysh layout [s][k][d] (half)
__global__ void __launch_bounds__(256) kc_apply(
        const _Float16* __restrict__ Zsh, const _Float16* __restrict__ xcTh,
        const _Float16* __restrict__ Y2h, const float* __restrict__ A_log,
        const float* __restrict__ D_skip, const _Float16* __restrict__ Pbh,
        _Float16* __restrict__ ysh) {
    int t = blockIdx.x * 256 + threadIdx.x;
    int nq = t & 3;
    int q = t >> 2;
    int d = q % 96;
    int rest = q / 96;
    int chunk = rest % NCHUNK;
    int k = rest / NCHUNK;
    int kb = (k < 3) ? k : (k - 3);
    bool flip = (k >= 3);
    float An[4];
    {
        float4 al = *(const float4*)(A_log + ((size_t)k * 96 + d) * 16 + nq * 4);
        An[0] = -__expf(al.x); An[1] = -__expf(al.y);
        An[2] = -__expf(al.z); An[3] = -__expf(al.w);
    }
    float Dk = D_skip[k * DDIM + d];
    float h[4];
    {
        half4v hp = *(const half4v*)(Pbh + (((size_t)k * NCHUNK + chunk) * 96 + d) * 16 + nq * 4);
        h[0] = (float)hp.x; h[1] = (float)hp.y; h[2] = (float)hp.z; h[3] = (float)hp.w;
    }
    const _Float16* Zk = Zsh + (size_t)k * L * 96;
    const _Float16* Yk = Y2h + (size_t)k * L * YH;
    int l0 = chunk * CHLEN;
    for (int i = 0; i < CHLEN; i += 4) {
        int sI[4]; float dt[4], xv[4]; half4v Bh[4], Ch[4];
#pragma unroll
        for (int j = 0; j < 4; j++) {
            int l = l0 + i + j;
            int lp = flip ? (4095 - l) : l;
            sI[j] = sigma_k(kb, lp);
        }
#pragma unroll
        for (int j = 0; j < 4; j++) {
            dt[j] = (float)Zk[(size_t)sI[j] * 96 + d];
            xv[j] = (float)xcTh[(size_t)sI[j] * 96 + d];
            Bh[j] = *(const half4v*)(Yk + (size_t)sI[j] * YH + nq * 4);
            Ch[j] = *(const half4v*)(Yk + (size_t)sI[j] * YH + 16 + nq * 4);
        }
#pragma unroll
        for (int j = 0; j < 4; j++) {
            float dtx = dt[j] * xv[j];
            float e0 = __expf(dt[j] * An[0]);
            float e1 = __expf(dt[j] * An[1]);
            float e2 = __expf(dt[j] * An[2]);
            float e3 = __expf(dt[j] * An[3]);
            h[0] = e0 * h[0] + dtx * (float)Bh[j].x;
            h[1] = e1 * h[1] + dtx * (float)Bh[j].y;
            h[2] = e2 * h[2] + dtx * (float)Bh[j].z;
            h[3] = e3 * h[3] + dtx * (float)Bh[j].w;
            float p = h[0] * (float)Ch[j].x + h[1] * (float)Ch[j].y
                    + h[2] * (float)Ch[j].z + h[3] * (float)Ch[j].w;
            p += __shfl_xor(p, 1);
            p += __shfl_xor(p, 2);
            if (nq == 0) ysh[((size_t)sI[j] * KDIR + k) * 96 + d] = (_Float16)(p + Dk * xv[j]);
        }
    }
}

// K6: weight-in-registers out stage. 8 s-rows per block, 192 thr, grid 512.
__global__ void __launch_bounds__(192) k6_out(
        const _Float16* __restrict__ ysh, const _Float16* __restrict__ zsh,
        const float* __restrict__ onw, const float* __restrict__ onb,
        const float* __restrict__ Wo, const float* __restrict__ x,
        float* __restrict__ out) {
    int s0 = blockIdx.x * 8;
    int tid = threadIdx.x;
    __shared__ __align__(16) float vt[8][96];
    __shared__ __align__(16) float gt[8][96];
    __shared__ float mss[8], rss[8];
#pragma unroll
    for (int j = 0; j < 4; j++) {
        int f = tid + j * 192;           // < 768
        int sr = f / 96, c = f % 96;
        const _Float16* yr = ysh + ((size_t)(s0 + sr) * KDIR) * 96 + c;
        float v = 0.f;
#pragma unroll
        for (int k = 0; k < KDIR; k++) v += (float)yr[k * 96];
        vt[sr][c] = v;
    }
    __syncthreads();
    int wave = tid >> 6, lane = tid & 63;
    for (int r = wave; r < 8; r += 3) {
        float v = vt[r][lane] + ((lane < 32) ? vt[r][64 + lane] : 0.f);
#pragma unroll
        for (int off = 1; off < 64; off <<= 1) v += __shfl_xor(v, off);
        float vs = vt[r][lane] * vt[r][lane] + ((lane < 32) ? vt[r][64 + lane] * vt[r][64 + lane] : 0.f);
#pragma unroll
        for (int off = 1; off < 64; off <<= 1) vs += __shfl_xor(vs, off);
        if (lane == 0) {
            float mean = v * (1.f / 96.f);
            float var = vs * (1.f / 96.f) - mean * mean;
            mss[r] = mean; rss[r] = rsqrtf(var + 1e-5f);
        }
    }
    __syncthreads();
#pragma unroll
    for (int j = 0; j < 4; j++) {
        int f = tid + j * 192;
        int sr = f / 96, c = f % 96;
        float g = (vt[sr][c] - mss[sr]) * rss[sr] * onw[c] + onb[c];
        gt[sr][c] = g * (float)zsh[(size_t)(s0 + sr) * 96 + c];
    }
    int e = tid % 96, sg = tid / 96;  // sg in {0,1}
    float4 Wr[24];
    const float4* wr = (const float4*)(Wo + (size_t)e * 96);
#pragma unroll
    for (int c4 = 0; c4 < 24; c4++) Wr[c4] = wr[c4];
    __syncthreads();
#pragma unroll
    for (int j = 0; j < 4; j++) {
        int s = sg * 4 + j;
        const float4* g4 = (const float4*)&gt[s][0];
        float a0 = 0.f, a1 = 0.f, a2 = 0.f, a3 = 0.f;
#pragma unroll
        for (int c4 = 0; c4 < 24; c4 += 4) {
            float4 x0 = g4[c4], x1 = g4[c4 + 1], x2 = g4[c4 + 2], x3 = g4[c4 + 3];
            a0 += Wr[c4].x * x0.x + Wr[c4].y * x0.y + Wr[c4].z * x0.z + Wr[c4].w * x0.w;
            a1 += Wr[c4+1].x * x1.x + Wr[c4+1].y * x1.y + Wr[c4+1].z * x1.z + Wr[c4+1].w * x1.w;
            a2 += Wr[c4+2].x * x2.x + Wr[c4+2].y * x2.y + Wr[c4+2].z * x2.z + Wr[c4+2].w * x2.w;
            a3 += Wr[c4+3].x * x3.x + Wr[c4+3].y * x3.y + Wr[c4+3].z * x3.z + Wr[c4+3].w * x3.w;
        }
        float acc = (a0 + a1) + (a2 + a3) + x[(size_t)(s0 + s) * 96 + e];
        out[(size_t)(s0 + s) * 96 + e] = acc;
    }
}

extern "C" void kernel_launch(void* const* d_in, const int* in_sizes, int n_in,
                              void* d_out, int out_size, void* d_ws, size_t ws_size,
                              hipStream_t stream) {
    const float* x        = (const float*)d_in[0];
    const float* ln1_w    = (const float*)d_in[1];
    const float* ln1_b    = (const float*)d_in[2];
    const float* in_proj  = (const float*)d_in[3];
    const float* conv_w   = (const float*)d_in[4];
    const float* conv_b   = (const float*)d_in[5];
    const float* x_proj   = (const float*)d_in[6];
    const float* dt_w     = (const float*)d_in[7];
    const float* dt_b     = (const float*)d_in[8];
    const float* A_log    = (const float*)d_in[9];
    const float* D_skip   = (const float*)d_in[10];
    const float* onw      = (const float*)d_in[11];
    const float* onb      = (const float*)d_in[12];
    const float* out_w    = (const float*)d_in[13];
    float* out = (float*)d_out;

    _Float16* xhh  = (_Float16*)d_ws;                 // 96*4096
    _Float16* zsh  = xhh + (size_t)96 * L;            // 4096*96
    _Float16* xch  = zsh + (size_t)96 * L;            // 96*4096
    _Float16* xcTh = xch + (size_t)96 * L;            // 4096*96
    _Float16* Y2h  = xcTh + (size_t)96 * L;           // 6*4096*32
    _Float16* Zsh  = Y2h + (size_t)KDIR * L * YH;     // 6*4096*96
    _Float16* ysh  = Zsh + (size_t)KDIR * L * 96;     // 4096*6*96
    _Float16* Aah  = ysh + (size_t)L * KDIR * 96;     // 6*256*96*16
    _Float16* Abh  = Aah + (size_t)KDIR * NCHUNK * DDIM * NST;
    _Float16* Pbh  = Abh + (size_t)KDIR * NCHUNK * DDIM * NST;

    k1_ln_inproj<<<dim3(L / 8), dim3(192), 0, stream>>>(x, ln1_w, ln1_b, in_proj, xhh, zsh);
    k2_conv<<<dim3(96 * L / 256), dim3(256), 0, stream>>>(xhh, conv_w, conv_b, xch, xcTh);
    k3_xproj<<<dim3(KDIR, 16, 4), dim3(256), 0, stream>>>(xch, x_proj, dt_w, dt_b, Y2h, Zsh);
    ka_scan<<<dim3(KDIR * NCHUNK * DDIM * 4 / 256), dim3(256), 0, stream>>>(Zsh, xcTh, Y2h, A_log, Aah, Abh);
    kb_combine<<<dim3(KDIR * DDIM * NST / 256), dim3(256), 0, stream>>>(Aah, Abh, Pbh);
    kc_apply<<<dim3(KDIR * NCHUNK * DDIM * 4 / 256), dim3(256), 0, stream>>>(Zsh, xcTh, Y2h, A_log, D_skip, Pbh, ysh);
    k6_out<<<dim3(L / 8), dim3(192), 0, stream>>>(ysh, zsh, onw, onb, out_w, x, out);
}